// Round 3
// baseline (1925.534 us; speedup 1.0000x reference)
//
#include <hip/hip_runtime.h>
#include <math.h>

typedef __bf16 bf16_t;
typedef __bf16 bf16x8 __attribute__((ext_vector_type(8)));
typedef float  floatx4 __attribute__((ext_vector_type(4)));

#define D_MODEL 2048
#define NH      8
#define DQK     128
#define DV      256
#define SEQ     2048
#define MROWS   4096        // B*S
#define QKVO_N  6144        // q(1024) | k(1024) | v(2048) | o_pre(2048)
#define FF      8192

// ---------------------------------------------------------------- utilities

__device__ __forceinline__ void glds16(const void* g, void* l) {
  __builtin_amdgcn_global_load_lds(
      (const __attribute__((address_space(1))) void*)g,
      (__attribute__((address_space(3))) void*)l, 16, 0, 0);
}

// ------------------------------------------------- transpose f32 -> bf16 ^T
// in: [K][N] f32 row-major; out: [N][K] bf16 row-major
// ILV=1: output row mapping n -> ((n>>4)<<5) + (n&15) + ioff  (16-col interleave
// of two matrices into one, for the fused gate/up GEMM)
template<int ILV>
__global__ __launch_bounds__(256) void transpose_bf16_kernel(
    const float* __restrict__ in, bf16_t* __restrict__ out, int K, int N, int ioff) {
  __shared__ float tile[64][65];
  int n0 = blockIdx.x * 64, k0 = blockIdx.y * 64;
  int tx = threadIdx.x & 63, tg = threadIdx.x >> 6;
#pragma unroll
  for (int i = tg; i < 64; i += 4)
    tile[i][tx] = in[(size_t)(k0 + i) * N + n0 + tx];
  __syncthreads();
#pragma unroll
  for (int i = tg; i < 64; i += 4) {
    int n = n0 + i;
    size_t orow = ILV ? (size_t)(((n >> 4) << 5) + (n & 15) + ioff) : (size_t)n;
    out[orow * K + k0 + tx] = (bf16_t)tile[tx][i];
  }
}

// ------------------------------------------- transpose v (bf16) -> [dv][s]
// in: qkvo [bs][6144], v block at +2048 ; out: vt[bh][dv][s]
__global__ __launch_bounds__(256) void vtrans_kernel(
    const bf16_t* __restrict__ qkvo, bf16_t* __restrict__ vt) {
  __shared__ bf16_t tile[64 * 64];  // XOR-swizzled [d][s]
  int s0 = blockIdx.x * 64;         // 32
  int d0 = blockIdx.y * 64;         // 4
  int bh = blockIdx.z;              // 16
  int b = bh >> 3, h = bh & 7;
  int tid = threadIdx.x;
  int r = tid >> 3, c8 = tid & 7;
#pragma unroll
  for (int u = 0; u < 2; ++u) {
    int rr = r + u * 32;  // s index
    bf16x8 v = *(const bf16x8*)&qkvo[(size_t)(b * SEQ + s0 + rr) * QKVO_N +
                                     2048 + h * DV + d0 + c8 * 8];
#pragma unroll
    for (int e = 0; e < 8; ++e) {
      int d = c8 * 8 + e;
      tile[d * 64 + (rr ^ ((e ^ c8) * 8))] = v[e];
    }
  }
  __syncthreads();
#pragma unroll
  for (int u = 0; u < 2; ++u) {
    int rr = r + u * 32;  // d index
    int cc = (c8 ^ (rr & 7) ^ ((rr >> 3) & 7)) * 8;
    bf16x8 v = *(const bf16x8*)&tile[rr * 64 + cc];
    *(bf16x8*)&vt[((size_t)bh * DV + d0 + rr) * SEQ + s0 + c8 * 8] = v;
  }
}

// --------------------------------------------- RMSNorm (+ fused gate dots)
template<bool GATES>
__global__ __launch_bounds__(256) void rmsnorm_kernel(
    const float* __restrict__ xin, const float* __restrict__ w,
    bf16_t* __restrict__ out,
    const float* __restrict__ w_ig, const float* __restrict__ b_ig,
    const float* __restrict__ w_fg, const float* __restrict__ b_fg,
    float* __restrict__ gate_pre) {
  int row = blockIdx.x, tid = threadIdx.x;
  int lane = tid & 63, wvi = tid >> 6;
  const float* xr = xin + (size_t)row * D_MODEL;
  floatx4 v0 = *(const floatx4*)&xr[tid * 8];
  floatx4 v1 = *(const floatx4*)&xr[tid * 8 + 4];
  float ss = 0.f;
#pragma unroll
  for (int e = 0; e < 4; ++e) ss += v0[e] * v0[e] + v1[e] * v1[e];
#pragma unroll
  for (int off = 32; off > 0; off >>= 1) ss += __shfl_down(ss, off, 64);
  __shared__ float red[4];
  if (lane == 0) red[wvi] = ss;
  __syncthreads();
  float scale = rsqrtf((red[0] + red[1] + red[2] + red[3]) * (1.0f / D_MODEL) + 1e-6f);
  floatx4 w0 = *(const floatx4*)&w[tid * 8];
  floatx4 w1 = *(const floatx4*)&w[tid * 8 + 4];
  float h[8];
#pragma unroll
  for (int e = 0; e < 4; ++e) { h[e] = v0[e] * w0[e] * scale; h[4 + e] = v1[e] * w1[e] * scale; }
  bf16x8 ob;
#pragma unroll
  for (int e = 0; e < 8; ++e) ob[e] = (bf16_t)h[e];
  *(bf16x8*)&out[(size_t)row * D_MODEL + tid * 8] = ob;
  if constexpr (GATES) {
    float pg[16];
#pragma unroll
    for (int j = 0; j < 16; ++j) pg[j] = 0.f;
    int c0 = tid * 8;
#pragma unroll
    for (int e = 0; e < 8; ++e) {
      const float* wi = w_ig + (size_t)(c0 + e) * NH;
      const float* wf = w_fg + (size_t)(c0 + e) * NH;
#pragma unroll
      for (int j = 0; j < 8; ++j) { pg[j] += h[e] * wi[j]; pg[8 + j] += h[e] * wf[j]; }
    }
#pragma unroll
    for (int j = 0; j < 16; ++j) {
#pragma unroll
      for (int off = 32; off > 0; off >>= 1) pg[j] += __shfl_down(pg[j], off, 64);
    }
    __shared__ float redg[4][16];
    if (lane == 0) {
#pragma unroll
      for (int j = 0; j < 16; ++j) redg[wvi][j] = pg[j];
    }
    __syncthreads();
    if (tid < 16) {
      float t = redg[0][tid] + redg[1][tid] + redg[2][tid] + redg[3][tid];
      float bias = (tid < 8) ? b_ig[tid] : b_fg[tid - 8];
      gate_pre[(size_t)row * 16 + tid] = 15.0f * tanhf((t + bias) * (1.0f / 15.0f));
    }
  }
}

// -------------------------------------------------------------- gate scan
__global__ __launch_bounds__(64) void gate_scan_kernel(
    const float* __restrict__ gate_pre, float* __restrict__ ftb,
    float* __restrict__ Gb, float* __restrict__ mb) {
  int bh = blockIdx.x;          // 0..15
  int b = bh >> 3, h = bh & 7;
  int lane = threadIdx.x;       // 0..63
  const int CH = SEQ / 64;      // 32
  float lf[CH], iv[CH];
  float ls = 0.f;
#pragma unroll
  for (int c = 0; c < CH; ++c) {
    int s = lane * CH + c;
    const float* gp = &gate_pre[(size_t)(b * SEQ + s) * 16];
    float fg = gp[8 + h];
    iv[c] = gp[h];
    float v = fminf(fg, 0.f) - log1pf(expf(-fabsf(fg)));
    lf[c] = v; ls += v;
  }
  float xs = ls;
#pragma unroll
  for (int off = 1; off < 64; off <<= 1) {
    float y = __shfl_up(xs, off, 64);
    if (lane >= off) xs += y;
  }
  float F0 = xs - ls;   // exclusive prefix
  float Fc = F0, Gv[CH], Fcs[CH], lmax = -3.0e38f;
#pragma unroll
  for (int c = 0; c < CH; ++c) {
    Fc += lf[c]; Fcs[c] = Fc;
    float g = iv[c] - Fc; Gv[c] = g;
    lmax = fmaxf(lmax, g);
  }
  float mx = lmax;
#pragma unroll
  for (int off = 1; off < 64; off <<= 1) {
    float y = __shfl_up(mx, off, 64);
    if (lane >= off) mx = fmaxf(mx, y);
  }
  float prev = __shfl_up(mx, 1, 64);
  if (lane == 0) prev = -3.0e38f;
  float run = prev;
  size_t base = (size_t)bh * SEQ + lane * CH;
  const float LOG_ISQ = -2.42601515f;  // log(1/sqrt(128))
#pragma unroll
  for (int c = 0; c < CH; ++c) {
    run = fmaxf(run, Gv[c]);
    ftb[base + c] = -run + LOG_ISQ;
    Gb[base + c]  = Gv[c];
    mb[base + c]  = Fcs[c] + run;
  }
}

// ------------------------------------------------------------- MFMA GEMM (LDS path)
// C[M,N] = A[M,K](bf16) * Bt[N,K](bf16)^T ; 128x128 tile, 4 waves, BK=32
// EPI: 0 = store bf16 to Cb; 1 = Cf = Xres + acc (f32); 3 = Cf += acc
template<int EPI>
__global__ __launch_bounds__(256) void gemm_kernel(
    const bf16_t* __restrict__ A, const bf16_t* __restrict__ Bt,
    int N, int K,
    float* __restrict__ Cf, const float* __restrict__ Xres,
    bf16_t* __restrict__ Cb) {
  __shared__ bf16_t sA[128 * 32];
  __shared__ bf16_t sB[128 * 32];
  int tid = threadIdx.x;
  int wv = tid >> 6, lane = tid & 63;
  int m0 = blockIdx.y * 128, n0 = blockIdx.x * 128;
  int lrow = lane >> 2, lseg = lane & 3;
  const bf16_t* gA = A + (size_t)(m0 + wv * 16 + lrow) * K + lseg * 8;
  const bf16_t* gB = Bt + (size_t)(n0 + wv * 16 + lrow) * K + lseg * 8;
  bf16_t* lA0 = &sA[(wv * 16) * 32];
  bf16_t* lA1 = &sA[(wv * 16 + 64) * 32];
  bf16_t* lB0 = &sB[(wv * 16) * 32];
  bf16_t* lB1 = &sB[(wv * 16 + 64) * 32];
  size_t skip = (size_t)64 * K;

  int wm = wv & 1, wn = wv >> 1;
  int r16 = lane & 15, q4 = lane >> 4;
  floatx4 acc[4][4];
#pragma unroll
  for (int i = 0; i < 4; ++i)
#pragma unroll
    for (int j = 0; j < 4; ++j) {
      acc[i][j][0] = 0.f; acc[i][j][1] = 0.f; acc[i][j][2] = 0.f; acc[i][j][3] = 0.f;
    }

  int niter = K >> 5;
  for (int kt = 0; kt < niter; ++kt) {
    const bf16_t* pA = gA + kt * 32;
    const bf16_t* pB = gB + kt * 32;
    glds16(pA, lA0);
    glds16(pA + skip, lA1);
    glds16(pB, lB0);
    glds16(pB + skip, lB1);
    __syncthreads();
    bf16x8 af[4], bfr[4];
#pragma unroll
    for (int i = 0; i < 4; ++i)
      af[i] = *(const bf16x8*)&sA[(wm * 64 + i * 16 + r16) * 32 + q4 * 8];
#pragma unroll
    for (int j = 0; j < 4; ++j)
      bfr[j] = *(const bf16x8*)&sB[(wn * 64 + j * 16 + r16) * 32 + q4 * 8];
#pragma unroll
    for (int i = 0; i < 4; ++i)
#pragma unroll
      for (int j = 0; j < 4; ++j)
        acc[i][j] = __builtin_amdgcn_mfma_f32_16x16x32_bf16(af[i], bfr[j], acc[i][j], 0, 0, 0);
    __syncthreads();
  }
#pragma unroll
  for (int i = 0; i < 4; ++i) {
#pragma unroll
    for (int r = 0; r < 4; ++r) {
      int grow = m0 + wm * 64 + i * 16 + q4 * 4 + r;
      size_t rb = (size_t)grow * N;
#pragma unroll
      for (int j = 0; j < 4; ++j) {
        int gcol = n0 + wn * 64 + j * 16 + r16;
        float v = acc[i][j][r];
        if constexpr (EPI == 0) {
          Cb[rb + gcol] = (bf16_t)v;
        } else if constexpr (EPI == 1) {
          Cf[rb + gcol] = Xres[rb + gcol] + v;
        } else {
          Cf[rb + gcol] += v;
        }
      }
    }
  }
}

// ------------------------------------------------- direct-global MFMA GEMM
// No LDS, no barriers in the K-loop: each wave loads its A/B fragments
// directly from global (16B/lane); intra-block duplicate reads hit L1/L2.
// EPI 5: fused gate/up — Bt is 16-col interleaved (even 16-block = gate,
// odd = up); epilogue computes silu(g)*u and stores bf16 [M][N/2].
template<int EPI>
__global__ __launch_bounds__(256) void gemm_dg_kernel(
    const bf16_t* __restrict__ A, const bf16_t* __restrict__ Bt,
    int N, int K,
    float* __restrict__ Cf, bf16_t* __restrict__ Cb) {
  int tid = threadIdx.x;
  int wv = tid >> 6, lane = tid & 63;
  int r16 = lane & 15, q4 = lane >> 4;
  int wm = wv & 1, wn = wv >> 1;
  int m0 = blockIdx.y * 128, n0 = blockIdx.x * 128;
  const bf16_t* pA = A + (size_t)(m0 + wm * 64 + r16) * K + q4 * 8;
  const bf16_t* pB = Bt + (size_t)(n0 + wn * 64 + r16) * K + q4 * 8;
  size_t rstep = (size_t)16 * K;

  floatx4 acc[4][4];
#pragma unroll
  for (int i = 0; i < 4; ++i)
#pragma unroll
    for (int j = 0; j < 4; ++j) {
      acc[i][j][0] = 0.f; acc[i][j][1] = 0.f; acc[i][j][2] = 0.f; acc[i][j][3] = 0.f;
    }

#pragma unroll 2
  for (int k = 0; k < K; k += 32) {
    bf16x8 af[4], bfr[4];
#pragma unroll
    for (int i = 0; i < 4; ++i) af[i] = *(const bf16x8*)(pA + i * rstep + k);
#pragma unroll
    for (int j = 0; j < 4; ++j) bfr[j] = *(const bf16x8*)(pB + j * rstep + k);
#pragma unroll
    for (int i = 0; i < 4; ++i)
#pragma unroll
      for (int j = 0; j < 4; ++j)
        acc[i][j] = __builtin_amdgcn_mfma_f32_16x16x32_bf16(af[i], bfr[j], acc[i][j], 0, 0, 0);
  }

#pragma unroll
  for (int i = 0; i < 4; ++i) {
#pragma unroll
    for (int r = 0; r < 4; ++r) {
      int grow = m0 + wm * 64 + i * 16 + q4 * 4 + r;
      if constexpr (EPI == 5) {
        size_t rb = (size_t)grow * (N >> 1);
#pragma unroll
        for (int jj = 0; jj < 2; ++jj) {
          float g = acc[i][2 * jj][r];
          float u = acc[i][2 * jj + 1][r];
          int c = (blockIdx.x * 4 + wn * 2 + jj) * 16 + r16;
          Cb[rb + c] = (bf16_t)((g / (1.f + __expf(-g))) * u);
        }
      } else {  // EPI == 3
        size_t rb = (size_t)grow * N;
#pragma unroll
        for (int j = 0; j < 4; ++j) {
          int gcol = n0 + wn * 64 + j * 16 + r16;
          Cf[rb + gcol] += acc[i][j][r];
        }
      }
    }
  }
}

// ------------------------------------------------------------- attention
__global__ __launch_bounds__(256) void attn_kernel(
    const bf16_t* __restrict__ qkvo, const bf16_t* __restrict__ vt,
    const float* __restrict__ ftb, const float* __restrict__ Gb,
    const float* __restrict__ mb, const float* __restrict__ mh_w,
    bf16_t* __restrict__ h_out) {
  constexpr int PS = 72;  // sP stride (16B-aligned rows)
  __shared__ bf16_t sP[32 * PS];
  __shared__ float sRS[32][2];
  __shared__ float sMS[32][4];
  __shared__ float sInvN[32];
  __shared__ float sSc[32];
  int p = blockIdx.x, bh = blockIdx.y;
  int b = bh >> 3, h = bh & 7;
  int tid = threadIdx.x;
  int wv = tid >> 6, lane = tid & 63;
  int r16 = lane & 15, q4 = lane >> 4;
  int mf = wv & 1, nh = wv >> 1;
  int dvb = wv * 64;
  size_t bh_off = (size_t)bh * SEQ;

  float mw[4];
#pragma unroll
  for (int nf = 0; nf < 4; ++nf) mw[nf] = mh_w[h * DV + dvb + nf * 16 + r16];

  for (int half = 0; half < 2; ++half) {
    int tt = half ? (63 - p) : p;
    int t0 = tt * 32;
    __syncthreads();
    bf16x8 qf[4];
    {
      const bf16_t* qrow =
          qkvo + (size_t)(b * SEQ + t0 + mf * 16 + r16) * QKVO_N + h * DQK + q4 * 8;
#pragma unroll
      for (int kt = 0; kt < 4; ++kt) qf[kt] = *(const bf16x8*)(qrow + kt * 32);
    }
    float ft[4];
#pragma unroll
    for (int r = 0; r < 4; ++r) ft[r] = ftb[bh_off + t0 + mf * 16 + q4 * 4 + r];

    floatx4 Of[2][4];
#pragma unroll
    for (int i = 0; i < 2; ++i)
#pragma unroll
      for (int j = 0; j < 4; ++j) Of[i][j] = (floatx4){0.f, 0.f, 0.f, 0.f};
    float rs[4] = {0.f, 0.f, 0.f, 0.f};

    int nst = (tt >> 1) + 1;
    const bf16_t* kp =
        qkvo + (size_t)(b * SEQ + nh * 32 + r16) * QKVO_N + 1024 + h * DQK + q4 * 8;
    const bf16_t* vp = vt + ((size_t)bh * DV + dvb + r16) * SEQ + q4 * 8;
    for (int st = 0; st < nst; ++st) {
      int s0 = st * 64;
      floatx4 sc[2] = {{0.f, 0.f, 0.f, 0.f}, {0.f, 0.f, 0.f, 0.f}};
#pragma unroll
      for (int nf = 0; nf < 2; ++nf) {
        const bf16_t* kpn = kp + (size_t)(s0 + nf * 16) * QKVO_N;
#pragma unroll
        for (int kt = 0; kt < 4; ++kt) {
          bf16x8 kf = *(const bf16x8*)(kpn + kt * 32);
          sc[nf] = __builtin_amdgcn_mfma_f32_16x16x32_bf16(qf[kt], kf, sc[nf], 0, 0, 0);
        }
      }
      bool diag = (st == nst - 1);
#pragma unroll
      for (int nf = 0; nf < 2; ++nf) {
        int scol = s0 + nh * 32 + nf * 16 + r16;
        float g = Gb[bh_off + scol];
#pragma unroll
        for (int r = 0; r < 4; ++r) {
          int trow = t0 + mf * 16 + q4 * 4 + r;
          float w = __expf(ft[r] + g) * sc[nf][r];
          if (diag && scol > trow) w = 0.f;
          rs[r] += w;
          sP[(mf * 16 + q4 * 4 + r) * PS + nh * 32 + nf * 16 + r16] = (bf16_t)w;
        }
      }
      __syncthreads();
      bf16x8 pa[2][2];
#pragma unroll
      for (int i = 0; i < 2; ++i)
#pragma unroll
        for (int kt = 0; kt < 2; ++kt)
          pa[i][kt] = *(const bf16x8*)&sP[(i * 16 + r16) * PS + kt * 32 + q4 * 8];
#pragma unroll
      for (int nf = 0; nf < 4; ++nf) {
        const bf16_t* vpn = vp + (size_t)(nf * 16) * SEQ + s0;
#pragma unroll
        for (int kt = 0; kt < 2; ++kt) {
          bf16x8 vf = *(const bf16x8*)(vpn + kt * 32);
#pragma unroll
          for (int i = 0; i < 2; ++i)
            Of[i][nf] = __builtin_amdgcn_mfma_f32_16x16x32_bf16(pa[i][kt], vf, Of[i][nf], 0, 0, 0);
        }
      }
      __syncthreads();
    }
#pragma unroll
    for (int r = 0; r < 4; ++r) {
#pragma unroll
      for (int off = 1; off < 16; off <<= 1) rs[r] += __shfl_xor(rs[r], off, 16);
    }
    if (r16 == 0) {
#pragma unroll
      for (int r = 0; r < 4; ++r) sRS[mf * 16 + q4 * 4 + r][nh] = rs[r];
    }
    __syncthreads();
    if (tid < 32) {
      float s = sRS[tid][0] + sRS[tid][1];
      sInvN[tid] = 1.0f / fmaxf(fabsf(s), __expf(-mb[bh_off + t0 + tid]));
    }
    __syncthreads();
    float msq[2][4] = {{0.f, 0.f, 0.f, 0.f}, {0.f, 0.f, 0.f, 0.f}};
#pragma unroll
    for (int i = 0; i < 2; ++i) {
#pragma unroll
      for (int r = 0; r < 4; ++r) {
        float inv = sInvN[i * 16 + q4 * 4 + r];
#pragma unroll
        for (int nf = 0; nf < 4; ++nf) {
          float v = Of[i][nf][r] * inv;
          Of[i][nf][r] = v;
          msq[i][r] += v * v;
        }
      }
    }
#pragma unroll
    for (int i = 0; i < 2; ++i)
#pragma unroll
      for (int r = 0; r < 4; ++r) {
#pragma unroll
        for (int off = 1; off < 16; off <<= 1) msq[i][r] += __shfl_xor(msq[i][r], off, 16);
      }
    if (r16 == 0) {
#pragma unroll
      for (int i = 0; i < 2; ++i)
#pragma unroll
        for (int r = 0; r < 4; ++r) sMS[i * 16 + q4 * 4 + r][wv] = msq[i][r];
    }
    __syncthreads();
    if (tid < 32) {
      float s = sMS[tid][0] + sMS[tid][1] + sMS[tid][2] + sMS[tid][3];
      sSc[tid] = rsqrtf(s * (1.0f / DV) + 1e-6f);
    }
    __syncthreads();
#pragma unroll
    for (int i = 0; i < 2; ++i) {
#pragma unroll
      for (int r = 0; r < 4; ++r) {
        int trow = t0 + i * 16 + q4 * 4 + r;
        size_t gr = (size_t)(b * SEQ + trow);
        float scl = sSc[i * 16 + q4 * 4 + r];
#pragma unroll
        for (int nf = 0; nf < 4; ++nf) {
          int col = h * DV + dvb + nf * 16 + r16;
          float op = (float)qkvo[gr * QKVO_N + 4096 + col];
          float sig = 1.0f / (1.0f + __expf(-op));
          h_out[gr * D_MODEL + col] = (bf16_t)(Of[i][nf][r] * scl * mw[nf] * sig);
        }
      }
    }
  }
}

// ---------------------------------------------------------------- launcher

extern "C" void kernel_launch(void* const* d_in, const int* in_sizes, int n_in,
                              void* d_out, int out_size, void* d_ws, size_t ws_size,
                              hipStream_t stream) {
  const float* x      = (const float*)d_in[0];
  const float* n1w    = (const float*)d_in[1];
  const float* wq     = (const float*)d_in[2];
  const float* wk     = (const float*)d_in[3];
  const float* wvp    = (const float*)d_in[4];
  const float* w_ig   = (const float*)d_in[5];
  const float* b_ig   = (const float*)d_in[6];
  const float* w_fg   = (const float*)d_in[7];
  const float* b_fg   = (const float*)d_in[8];
  const float* w_og   = (const float*)d_in[9];
  const float* mh_w   = (const float*)d_in[10];
  const float* w_out  = (const float*)d_in[11];
  const float* n2w    = (const float*)d_in[12];
  const float* w_gate = (const float*)d_in[13];
  const float* w_up   = (const float*)d_in[14];
  const float* w_down = (const float*)d_in[15];
  float* out = (float*)d_out;
  (void)in_sizes; (void)n_in; (void)out_size; (void)ws_size;

  char* base = (char*)d_ws;
  size_t off = 0;
  auto alloc = [&](size_t bytes) -> void* {
    void* pp = base + off;
    off += (bytes + 255) & ~(size_t)255;
    return pp;
  };
  bf16_t* wT_qkvo = (bf16_t*)alloc((size_t)QKVO_N * 2048 * 2);
  bf16_t* wT_out  = (bf16_t*)alloc((size_t)2048 * 2048 * 2);
  bf16_t* wT_gu   = (bf16_t*)alloc((size_t)2 * FF * 2048 * 2);  // 16-col interleaved gate|up
  bf16_t* wT_down = (bf16_t*)alloc((size_t)2048 * FF * 2);
  bf16_t* h_in    = (bf16_t*)alloc((size_t)MROWS * 2048 * 2);   // reused as h2; aliased by vtbuf
  float*  gate_pre= (float*)alloc((size_t)MROWS * 16 * 4);
  float*  ftb     = (float*)alloc((size_t)16 * SEQ * 4);
  float*  Gbuf    = (float*)alloc((size_t)16 * SEQ * 4);
  float*  mbuf    = (float*)alloc((size_t)16 * SEQ * 4);
  bf16_t* qkvo    = (bf16_t*)alloc((size_t)MROWS * QKVO_N * 2); // 48MB
  bf16_t* h_out   = (bf16_t*)alloc((size_t)MROWS * 2048 * 2);   // 16MB
  bf16_t* tbuf    = qkvo;   // alias qkvo+h_out (both dead by MLP time); [4096][8192] bf16
  bf16_t* vtbuf   = h_in;   // alias: h_in dead after qkvo GEMM, reborn at rmsnorm2

  dim3 blk(256);
  // weight transposes -> bf16 [N][K]
  transpose_bf16_kernel<0><<<dim3(16, 32), blk, 0, stream>>>(wq, wT_qkvo, 2048, 1024, 0);
  transpose_bf16_kernel<0><<<dim3(16, 32), blk, 0, stream>>>(wk, wT_qkvo + (size_t)1024 * 2048, 2048, 1024, 0);
  transpose_bf16_kernel<0><<<dim3(32, 32), blk, 0, stream>>>(wvp, wT_qkvo + (size_t)2048 * 2048, 2048, 2048, 0);
  transpose_bf16_kernel<0><<<dim3(32, 32), blk, 0, stream>>>(w_og, wT_qkvo + (size_t)4096 * 2048, 2048, 2048, 0);
  transpose_bf16_kernel<0><<<dim3(32, 32), blk, 0, stream>>>(w_out, wT_out, 2048, 2048, 0);
  transpose_bf16_kernel<1><<<dim3(128, 32), blk, 0, stream>>>(w_gate, wT_gu, 2048, FF, 0);
  transpose_bf16_kernel<1><<<dim3(128, 32), blk, 0, stream>>>(w_up, wT_gu, 2048, FF, 16);
  transpose_bf16_kernel<0><<<dim3(32, 128), blk, 0, stream>>>(w_down, wT_down, FF, 2048, 0);

  rmsnorm_kernel<true><<<MROWS, blk, 0, stream>>>(x, n1w, h_in, w_ig, b_ig, w_fg, b_fg, gate_pre);
  gate_scan_kernel<<<16, 64, 0, stream>>>(gate_pre, ftb, Gbuf, mbuf);

  gemm_kernel<0><<<dim3(QKVO_N / 128, 32), blk, 0, stream>>>(
      h_in, wT_qkvo, QKVO_N, 2048, nullptr, nullptr, qkvo);

  vtrans_kernel<<<dim3(32, 4, 16), blk, 0, stream>>>(qkvo, vtbuf);
  attn_kernel<<<dim3(32, 16), blk, 0, stream>>>(qkvo, vtbuf, ftb, Gbuf, mbuf, mh_w, h_out);

  gemm_kernel<1><<<dim3(16, 32), blk, 0, stream>>>(
      h_out, wT_out, 2048, 2048, out, x, nullptr);

  rmsnorm_kernel<false><<<MROWS, blk, 0, stream>>>(out, n2w, h_in,
      nullptr, nullptr, nullptr, nullptr, nullptr);

  // fused gate+up: N=16384 interleaved, epilogue silu(g)*u -> tbuf [4096][8192]
  gemm_dg_kernel<5><<<dim3(2 * FF / 128, 32), blk, 0, stream>>>(
      h_in, wT_gu, 2 * FF, 2048, nullptr, tbuf);
  gemm_kernel<3><<<dim3(16, 32), blk, 0, stream>>>(
      tbuf, wT_down, 2048, FF, out, nullptr, nullptr);
}

// Round 4
// 1276.318 us; speedup vs baseline: 1.5087x; 1.5087x over previous
//
#include <hip/hip_runtime.h>
#include <math.h>

typedef __bf16 bf16_t;
typedef __bf16 bf16x8 __attribute__((ext_vector_type(8)));
typedef float  floatx4 __attribute__((ext_vector_type(4)));

#define D_MODEL 2048
#define NH      8
#define DQK     128
#define DV      256
#define SEQ     2048
#define MROWS   4096        // B*S
#define QKVO_N  6144        // q(1024) | k(1024) | v(2048) | o_pre(2048)
#define FF      8192

// ---------------------------------------------------------------- utilities

__device__ __forceinline__ void glds16(const void* g, void* l) {
  __builtin_amdgcn_global_load_lds(
      (const __attribute__((address_space(1))) void*)g,
      (__attribute__((address_space(3))) void*)l, 16, 0, 0);
}

// ------------------------------------------------- transpose f32 -> bf16 ^T
// in: [K][N] f32 row-major; out: [N][K] bf16 row-major
// ILV=1: output row mapping n -> ((n>>4)<<5) + (n&15) + ioff  (16-col interleave
// of two matrices into one, for the fused gate/up GEMM)
template<int ILV>
__global__ __launch_bounds__(256) void transpose_bf16_kernel(
    const float* __restrict__ in, bf16_t* __restrict__ out, int K, int N, int ioff) {
  __shared__ float tile[64][65];
  int n0 = blockIdx.x * 64, k0 = blockIdx.y * 64;
  int tx = threadIdx.x & 63, tg = threadIdx.x >> 6;
#pragma unroll
  for (int i = tg; i < 64; i += 4)
    tile[i][tx] = in[(size_t)(k0 + i) * N + n0 + tx];
  __syncthreads();
#pragma unroll
  for (int i = tg; i < 64; i += 4) {
    int n = n0 + i;
    size_t orow = ILV ? (size_t)(((n >> 4) << 5) + (n & 15) + ioff) : (size_t)n;
    out[orow * K + k0 + tx] = (bf16_t)tile[tx][i];
  }
}

// ------------------------------------------- transpose v (bf16) -> [dv][s]
__global__ __launch_bounds__(256) void vtrans_kernel(
    const bf16_t* __restrict__ qkvo, bf16_t* __restrict__ vt) {
  __shared__ bf16_t tile[64 * 64];  // XOR-swizzled [d][s]
  int s0 = blockIdx.x * 64;         // 32
  int d0 = blockIdx.y * 64;         // 4
  int bh = blockIdx.z;              // 16
  int b = bh >> 3, h = bh & 7;
  int tid = threadIdx.x;
  int r = tid >> 3, c8 = tid & 7;
#pragma unroll
  for (int u = 0; u < 2; ++u) {
    int rr = r + u * 32;  // s index
    bf16x8 v = *(const bf16x8*)&qkvo[(size_t)(b * SEQ + s0 + rr) * QKVO_N +
                                     2048 + h * DV + d0 + c8 * 8];
#pragma unroll
    for (int e = 0; e < 8; ++e) {
      int d = c8 * 8 + e;
      tile[d * 64 + (rr ^ ((e ^ c8) * 8))] = v[e];
    }
  }
  __syncthreads();
#pragma unroll
  for (int u = 0; u < 2; ++u) {
    int rr = r + u * 32;  // d index
    int cc = (c8 ^ (rr & 7) ^ ((rr >> 3) & 7)) * 8;
    bf16x8 v = *(const bf16x8*)&tile[rr * 64 + cc];
    *(bf16x8*)&vt[((size_t)bh * DV + d0 + rr) * SEQ + s0 + c8 * 8] = v;
  }
}

// --------------------------------------------- RMSNorm (+ fused gate dots)
template<bool GATES>
__global__ __launch_bounds__(256) void rmsnorm_kernel(
    const float* __restrict__ xin, const float* __restrict__ w,
    bf16_t* __restrict__ out,
    const float* __restrict__ w_ig, const float* __restrict__ b_ig,
    const float* __restrict__ w_fg, const float* __restrict__ b_fg,
    float* __restrict__ gate_pre) {
  int row = blockIdx.x, tid = threadIdx.x;
  int lane = tid & 63, wvi = tid >> 6;
  const float* xr = xin + (size_t)row * D_MODEL;
  floatx4 v0 = *(const floatx4*)&xr[tid * 8];
  floatx4 v1 = *(const floatx4*)&xr[tid * 8 + 4];
  float ss = 0.f;
#pragma unroll
  for (int e = 0; e < 4; ++e) ss += v0[e] * v0[e] + v1[e] * v1[e];
#pragma unroll
  for (int off = 32; off > 0; off >>= 1) ss += __shfl_down(ss, off, 64);
  __shared__ float red[4];
  if (lane == 0) red[wvi] = ss;
  __syncthreads();
  float scale = rsqrtf((red[0] + red[1] + red[2] + red[3]) * (1.0f / D_MODEL) + 1e-6f);
  floatx4 w0 = *(const floatx4*)&w[tid * 8];
  floatx4 w1 = *(const floatx4*)&w[tid * 8 + 4];
  float h[8];
#pragma unroll
  for (int e = 0; e < 4; ++e) { h[e] = v0[e] * w0[e] * scale; h[4 + e] = v1[e] * w1[e] * scale; }
  bf16x8 ob;
#pragma unroll
  for (int e = 0; e < 8; ++e) ob[e] = (bf16_t)h[e];
  *(bf16x8*)&out[(size_t)row * D_MODEL + tid * 8] = ob;
  if constexpr (GATES) {
    float pg[16];
#pragma unroll
    for (int j = 0; j < 16; ++j) pg[j] = 0.f;
    int c0 = tid * 8;
#pragma unroll
    for (int e = 0; e < 8; ++e) {
      const float* wi = w_ig + (size_t)(c0 + e) * NH;
      const float* wf = w_fg + (size_t)(c0 + e) * NH;
#pragma unroll
      for (int j = 0; j < 8; ++j) { pg[j] += h[e] * wi[j]; pg[8 + j] += h[e] * wf[j]; }
    }
#pragma unroll
    for (int j = 0; j < 16; ++j) {
#pragma unroll
      for (int off = 32; off > 0; off >>= 1) pg[j] += __shfl_down(pg[j], off, 64);
    }
    __shared__ float redg[4][16];
    if (lane == 0) {
#pragma unroll
      for (int j = 0; j < 16; ++j) redg[wvi][j] = pg[j];
    }
    __syncthreads();
    if (tid < 16) {
      float t = redg[0][tid] + redg[1][tid] + redg[2][tid] + redg[3][tid];
      float bias = (tid < 8) ? b_ig[tid] : b_fg[tid - 8];
      gate_pre[(size_t)row * 16 + tid] = 15.0f * tanhf((t + bias) * (1.0f / 15.0f));
    }
  }
}

// -------------------------------------------------------------- gate scan
__global__ __launch_bounds__(64) void gate_scan_kernel(
    const float* __restrict__ gate_pre, float* __restrict__ ftb,
    float* __restrict__ Gb, float* __restrict__ mb) {
  int bh = blockIdx.x;          // 0..15
  int b = bh >> 3, h = bh & 7;
  int lane = threadIdx.x;       // 0..63
  const int CH = SEQ / 64;      // 32
  float lf[CH], iv[CH];
  float ls = 0.f;
#pragma unroll
  for (int c = 0; c < CH; ++c) {
    int s = lane * CH + c;
    const float* gp = &gate_pre[(size_t)(b * SEQ + s) * 16];
    float fg = gp[8 + h];
    iv[c] = gp[h];
    float v = fminf(fg, 0.f) - log1pf(expf(-fabsf(fg)));
    lf[c] = v; ls += v;
  }
  float xs = ls;
#pragma unroll
  for (int off = 1; off < 64; off <<= 1) {
    float y = __shfl_up(xs, off, 64);
    if (lane >= off) xs += y;
  }
  float F0 = xs - ls;   // exclusive prefix
  float Fc = F0, Gv[CH], Fcs[CH], lmax = -3.0e38f;
#pragma unroll
  for (int c = 0; c < CH; ++c) {
    Fc += lf[c]; Fcs[c] = Fc;
    float g = iv[c] - Fc; Gv[c] = g;
    lmax = fmaxf(lmax, g);
  }
  float mx = lmax;
#pragma unroll
  for (int off = 1; off < 64; off <<= 1) {
    float y = __shfl_up(mx, off, 64);
    if (lane >= off) mx = fmaxf(mx, y);
  }
  float prev = __shfl_up(mx, 1, 64);
  if (lane == 0) prev = -3.0e38f;
  float run = prev;
  size_t base = (size_t)bh * SEQ + lane * CH;
  const float LOG_ISQ = -2.42601515f;  // log(1/sqrt(128))
#pragma unroll
  for (int c = 0; c < CH; ++c) {
    run = fmaxf(run, Gv[c]);
    ftb[base + c] = -run + LOG_ISQ;
    Gb[base + c]  = Gv[c];
    mb[base + c]  = Fcs[c] + run;
  }
}

// ------------------------------------------------------------- MFMA GEMM
// C[M,N] = A[M,K](bf16) * Bt[N,K](bf16)^T ; 128x128 tile, 4 waves, BK=64,
// XOR-swizzled LDS (conflict-free b128 reads), GROUP_M=4 block swizzle (1D grid).
// M fixed = MROWS (32 m-tiles).
// EPI: 0 = store bf16 to Cb; 1 = Cf = Xres + acc; 3 = Cf += acc;
//      5 = fused gate/up: Bt 16-col interleaved, Cb[M][N/2] = silu(g)*u
template<int EPI>
__global__ __launch_bounds__(256) void gemm_kernel(
    const bf16_t* __restrict__ A, const bf16_t* __restrict__ Bt,
    int N, int K,
    float* __restrict__ Cf, const float* __restrict__ Xres,
    bf16_t* __restrict__ Cb) {
  __shared__ bf16_t sA[128 * 64];
  __shared__ bf16_t sB[128 * 64];
  int tid = threadIdx.x;
  int wv = tid >> 6, lane = tid & 63;
  // block swizzle: 4 consecutive ids share one B-tile across a 4-m-tile band
  int nTn = N >> 7;
  int id = blockIdx.x;
  int band = id / (4 * nTn);
  int rem = id - band * 4 * nTn;
  int mt = band * 4 + (rem & 3);
  int nt = rem >> 2;
  int m0 = mt * 128, n0 = nt * 128;

  // staging: wave wv covers rows [wv*32, wv*32+32); chunk c = 8 rows (1 KB).
  // lane l -> row lr=l>>3, swizzled col-chunk lc=(l&7)^lr (global side),
  // lands at lds row-major position (r, l&7) -> lds holds (r, q^r&7) global.
  int lr = lane >> 3;
  int lc = (lane & 7) ^ lr;
  const bf16_t* gA = A + (size_t)(m0 + wv * 32 + lr) * K + lc * 8;
  const bf16_t* gB = Bt + (size_t)(n0 + wv * 32 + lr) * K + lc * 8;
  bf16_t* lA = &sA[(wv * 32) * 64];
  bf16_t* lB = &sB[(wv * 32) * 64];
  size_t cstep = (size_t)8 * K;

  int wm = wv & 1, wn = wv >> 1;
  int r16 = lane & 15, q4 = lane >> 4;
  floatx4 acc[4][4];
#pragma unroll
  for (int i = 0; i < 4; ++i)
#pragma unroll
    for (int j = 0; j < 4; ++j) {
      acc[i][j][0] = 0.f; acc[i][j][1] = 0.f; acc[i][j][2] = 0.f; acc[i][j][3] = 0.f;
    }

  int niter = K >> 6;
  for (int kt = 0; kt < niter; ++kt) {
    const bf16_t* pA = gA + kt * 64;
    const bf16_t* pB = gB + kt * 64;
#pragma unroll
    for (int c = 0; c < 4; ++c) {
      glds16(pA + c * cstep, lA + c * 8 * 64);
      glds16(pB + c * cstep, lB + c * 8 * 64);
    }
    __syncthreads();
#pragma unroll
    for (int kk = 0; kk < 2; ++kk) {
      bf16x8 af[4], bfr[4];
#pragma unroll
      for (int i = 0; i < 4; ++i) {
        int rr = wm * 64 + i * 16 + r16;
        af[i] = *(const bf16x8*)&sA[rr * 64 + ((((kk << 2) | q4) ^ (rr & 7)) << 3)];
      }
#pragma unroll
      for (int j = 0; j < 4; ++j) {
        int rr = wn * 64 + j * 16 + r16;
        bfr[j] = *(const bf16x8*)&sB[rr * 64 + ((((kk << 2) | q4) ^ (rr & 7)) << 3)];
      }
#pragma unroll
      for (int i = 0; i < 4; ++i)
#pragma unroll
        for (int j = 0; j < 4; ++j)
          acc[i][j] = __builtin_amdgcn_mfma_f32_16x16x32_bf16(af[i], bfr[j], acc[i][j], 0, 0, 0);
    }
    __syncthreads();
  }
  // epilogue: C/D layout col=lane&15, row=(lane>>4)*4+reg
#pragma unroll
  for (int i = 0; i < 4; ++i) {
#pragma unroll
    for (int r = 0; r < 4; ++r) {
      int grow = m0 + wm * 64 + i * 16 + q4 * 4 + r;
      if constexpr (EPI == 5) {
        size_t rb = (size_t)grow * (N >> 1);
#pragma unroll
        for (int jj = 0; jj < 2; ++jj) {
          float g = acc[i][2 * jj][r];      // even 16-block = gate
          float u = acc[i][2 * jj + 1][r];  // odd  16-block = up
          int c = (nt * 4 + wn * 2 + jj) * 16 + r16;
          Cb[rb + c] = (bf16_t)((g / (1.f + __expf(-g))) * u);
        }
      } else {
        size_t rb = (size_t)grow * N;
#pragma unroll
        for (int j = 0; j < 4; ++j) {
          int gcol = n0 + wn * 64 + j * 16 + r16;
          float v = acc[i][j][r];
          if constexpr (EPI == 0) {
            Cb[rb + gcol] = (bf16_t)v;
          } else if constexpr (EPI == 1) {
            Cf[rb + gcol] = Xres[rb + gcol] + v;
          } else {
            Cf[rb + gcol] += v;
          }
        }
      }
    }
  }
}

// ------------------------------------------------------------- attention
__global__ __launch_bounds__(256) void attn_kernel(
    const bf16_t* __restrict__ qkvo, const bf16_t* __restrict__ vt,
    const float* __restrict__ ftb, const float* __restrict__ Gb,
    const float* __restrict__ mb, const float* __restrict__ mh_w,
    bf16_t* __restrict__ h_out) {
  constexpr int PS = 72;  // sP stride (16B-aligned rows)
  __shared__ bf16_t sP[32 * PS];
  __shared__ float sRS[32][2];
  __shared__ float sMS[32][4];
  __shared__ float sInvN[32];
  __shared__ float sSc[32];
  int p = blockIdx.x, bh = blockIdx.y;
  int b = bh >> 3, h = bh & 7;
  int tid = threadIdx.x;
  int wv = tid >> 6, lane = tid & 63;
  int r16 = lane & 15, q4 = lane >> 4;
  int mf = wv & 1, nh = wv >> 1;
  int dvb = wv * 64;
  size_t bh_off = (size_t)bh * SEQ;

  float mw[4];
#pragma unroll
  for (int nf = 0; nf < 4; ++nf) mw[nf] = mh_w[h * DV + dvb + nf * 16 + r16];

  for (int half = 0; half < 2; ++half) {
    int tt = half ? (63 - p) : p;
    int t0 = tt * 32;
    __syncthreads();
    bf16x8 qf[4];
    {
      const bf16_t* qrow =
          qkvo + (size_t)(b * SEQ + t0 + mf * 16 + r16) * QKVO_N + h * DQK + q4 * 8;
#pragma unroll
      for (int kt = 0; kt < 4; ++kt) qf[kt] = *(const bf16x8*)(qrow + kt * 32);
    }
    float ft[4];
#pragma unroll
    for (int r = 0; r < 4; ++r) ft[r] = ftb[bh_off + t0 + mf * 16 + q4 * 4 + r];

    floatx4 Of[2][4];
#pragma unroll
    for (int i = 0; i < 2; ++i)
#pragma unroll
      for (int j = 0; j < 4; ++j) Of[i][j] = (floatx4){0.f, 0.f, 0.f, 0.f};
    float rs[4] = {0.f, 0.f, 0.f, 0.f};

    int nst = (tt >> 1) + 1;
    const bf16_t* kp =
        qkvo + (size_t)(b * SEQ + nh * 32 + r16) * QKVO_N + 1024 + h * DQK + q4 * 8;
    const bf16_t* vp = vt + ((size_t)bh * DV + dvb + r16) * SEQ + q4 * 8;
    for (int st = 0; st < nst; ++st) {
      int s0 = st * 64;
      floatx4 sc[2] = {{0.f, 0.f, 0.f, 0.f}, {0.f, 0.f, 0.f, 0.f}};
#pragma unroll
      for (int nf = 0; nf < 2; ++nf) {
        const bf16_t* kpn = kp + (size_t)(s0 + nf * 16) * QKVO_N;
#pragma unroll
        for (int kt = 0; kt < 4; ++kt) {
          bf16x8 kf = *(const bf16x8*)(kpn + kt * 32);
          sc[nf] = __builtin_amdgcn_mfma_f32_16x16x32_bf16(qf[kt], kf, sc[nf], 0, 0, 0);
        }
      }
      bool diag = (st == nst - 1);
#pragma unroll
      for (int nf = 0; nf < 2; ++nf) {
        int scol = s0 + nh * 32 + nf * 16 + r16;
        float g = Gb[bh_off + scol];
#pragma unroll
        for (int r = 0; r < 4; ++r) {
          int trow = t0 + mf * 16 + q4 * 4 + r;
          float w = __expf(ft[r] + g) * sc[nf][r];
          if (diag && scol > trow) w = 0.f;
          rs[r] += w;
          sP[(mf * 16 + q4 * 4 + r) * PS + nh * 32 + nf * 16 + r16] = (bf16_t)w;
        }
      }
      __syncthreads();
      bf16x8 pa[2][2];
#pragma unroll
      for (int i = 0; i < 2; ++i)
#pragma unroll
        for (int kt = 0; kt < 2; ++kt)
          pa[i][kt] = *(const bf16x8*)&sP[(i * 16 + r16) * PS + kt * 32 + q4 * 8];
#pragma unroll
      for (int nf = 0; nf < 4; ++nf) {
        const bf16_t* vpn = vp + (size_t)(nf * 16) * SEQ + s0;
#pragma unroll
        for (int kt = 0; kt < 2; ++kt) {
          bf16x8 vf = *(const bf16x8*)(vpn + kt * 32);
#pragma unroll
          for (int i = 0; i < 2; ++i)
            Of[i][nf] = __builtin_amdgcn_mfma_f32_16x16x32_bf16(pa[i][kt], vf, Of[i][nf], 0, 0, 0);
        }
      }
      __syncthreads();
    }
#pragma unroll
    for (int r = 0; r < 4; ++r) {
#pragma unroll
      for (int off = 1; off < 16; off <<= 1) rs[r] += __shfl_xor(rs[r], off, 16);
    }
    if (r16 == 0) {
#pragma unroll
      for (int r = 0; r < 4; ++r) sRS[mf * 16 + q4 * 4 + r][nh] = rs[r];
    }
    __syncthreads();
    if (tid < 32) {
      float s = sRS[tid][0] + sRS[tid][1];
      sInvN[tid] = 1.0f / fmaxf(fabsf(s), __expf(-mb[bh_off + t0 + tid]));
    }
    __syncthreads();
    float msq[2][4] = {{0.f, 0.f, 0.f, 0.f}, {0.f, 0.f, 0.f, 0.f}};
#pragma unroll
    for (int i = 0; i < 2; ++i) {
#pragma unroll
      for (int r = 0; r < 4; ++r) {
        float inv = sInvN[i * 16 + q4 * 4 + r];
#pragma unroll
        for (int nf = 0; nf < 4; ++nf) {
          float v = Of[i][nf][r] * inv;
          Of[i][nf][r] = v;
          msq[i][r] += v * v;
        }
      }
    }
#pragma unroll
    for (int i = 0; i < 2; ++i)
#pragma unroll
      for (int r = 0; r < 4; ++r) {
#pragma unroll
        for (int off = 1; off < 16; off <<= 1) msq[i][r] += __shfl_xor(msq[i][r], off, 16);
      }
    if (r16 == 0) {
#pragma unroll
      for (int i = 0; i < 2; ++i)
#pragma unroll
        for (int r = 0; r < 4; ++r) sMS[i * 16 + q4 * 4 + r][wv] = msq[i][r];
    }
    __syncthreads();
    if (tid < 32) {
      float s = sMS[tid][0] + sMS[tid][1] + sMS[tid][2] + sMS[tid][3];
      sSc[tid] = rsqrtf(s * (1.0f / DV) + 1e-6f);
    }
    __syncthreads();
#pragma unroll
    for (int i = 0; i < 2; ++i) {
#pragma unroll
      for (int r = 0; r < 4; ++r) {
        int trow = t0 + i * 16 + q4 * 4 + r;
        size_t gr = (size_t)(b * SEQ + trow);
        float scl = sSc[i * 16 + q4 * 4 + r];
#pragma unroll
        for (int nf = 0; nf < 4; ++nf) {
          int col = h * DV + dvb + nf * 16 + r16;
          float op = (float)qkvo[gr * QKVO_N + 4096 + col];
          float sig = 1.0f / (1.0f + __expf(-op));
          h_out[gr * D_MODEL + col] = (bf16_t)(Of[i][nf][r] * scl * mw[nf] * sig);
        }
      }
    }
  }
}

// ---------------------------------------------------------------- launcher

extern "C" void kernel_launch(void* const* d_in, const int* in_sizes, int n_in,
                              void* d_out, int out_size, void* d_ws, size_t ws_size,
                              hipStream_t stream) {
  const float* x      = (const float*)d_in[0];
  const float* n1w    = (const float*)d_in[1];
  const float* wq     = (const float*)d_in[2];
  const float* wk     = (const float*)d_in[3];
  const float* wvp    = (const float*)d_in[4];
  const float* w_ig   = (const float*)d_in[5];
  const float* b_ig   = (const float*)d_in[6];
  const float* w_fg   = (const float*)d_in[7];
  const float* b_fg   = (const float*)d_in[8];
  const float* w_og   = (const float*)d_in[9];
  const float* mh_w   = (const float*)d_in[10];
  const float* w_out  = (const float*)d_in[11];
  const float* n2w    = (const float*)d_in[12];
  const float* w_gate = (const float*)d_in[13];
  const float* w_up   = (const float*)d_in[14];
  const float* w_down = (const float*)d_in[15];
  float* out = (float*)d_out;
  (void)in_sizes; (void)n_in; (void)out_size; (void)ws_size;

  char* base = (char*)d_ws;
  size_t off = 0;
  auto alloc = [&](size_t bytes) -> void* {
    void* pp = base + off;
    off += (bytes + 255) & ~(size_t)255;
    return pp;
  };
  bf16_t* wT_qkvo = (bf16_t*)alloc((size_t)QKVO_N * 2048 * 2);
  bf16_t* wT_out  = (bf16_t*)alloc((size_t)2048 * 2048 * 2);
  bf16_t* wT_gu   = (bf16_t*)alloc((size_t)2 * FF * 2048 * 2);  // 16-col interleaved gate|up
  bf16_t* wT_down = (bf16_t*)alloc((size_t)2048 * FF * 2);
  bf16_t* h_in    = (bf16_t*)alloc((size_t)MROWS * 2048 * 2);   // reused as h2; aliased by vtbuf
  float*  gate_pre= (float*)alloc((size_t)MROWS * 16 * 4);
  float*  ftb     = (float*)alloc((size_t)16 * SEQ * 4);
  float*  Gbuf    = (float*)alloc((size_t)16 * SEQ * 4);
  float*  mbuf    = (float*)alloc((size_t)16 * SEQ * 4);
  bf16_t* qkvo    = (bf16_t*)alloc((size_t)MROWS * QKVO_N * 2); // 48MB
  bf16_t* h_out   = (bf16_t*)alloc((size_t)MROWS * 2048 * 2);   // 16MB
  bf16_t* tbuf    = qkvo;   // alias qkvo+h_out (both dead by MLP time); [4096][8192] bf16
  bf16_t* vtbuf   = h_in;   // alias: h_in dead after qkvo GEMM, reborn at rmsnorm2

  dim3 blk(256);
  // weight transposes -> bf16 [N][K]
  transpose_bf16_kernel<0><<<dim3(16, 32), blk, 0, stream>>>(wq, wT_qkvo, 2048, 1024, 0);
  transpose_bf16_kernel<0><<<dim3(16, 32), blk, 0, stream>>>(wk, wT_qkvo + (size_t)1024 * 2048, 2048, 1024, 0);
  transpose_bf16_kernel<0><<<dim3(32, 32), blk, 0, stream>>>(wvp, wT_qkvo + (size_t)2048 * 2048, 2048, 2048, 0);
  transpose_bf16_kernel<0><<<dim3(32, 32), blk, 0, stream>>>(w_og, wT_qkvo + (size_t)4096 * 2048, 2048, 2048, 0);
  transpose_bf16_kernel<0><<<dim3(32, 32), blk, 0, stream>>>(w_out, wT_out, 2048, 2048, 0);
  transpose_bf16_kernel<1><<<dim3(128, 32), blk, 0, stream>>>(w_gate, wT_gu, 2048, FF, 0);
  transpose_bf16_kernel<1><<<dim3(128, 32), blk, 0, stream>>>(w_up, wT_gu, 2048, FF, 16);
  transpose_bf16_kernel<0><<<dim3(32, 128), blk, 0, stream>>>(w_down, wT_down, FF, 2048, 0);

  rmsnorm_kernel<true><<<MROWS, blk, 0, stream>>>(x, n1w, h_in, w_ig, b_ig, w_fg, b_fg, gate_pre);
  gate_scan_kernel<<<16, 64, 0, stream>>>(gate_pre, ftb, Gbuf, mbuf);

  gemm_kernel<0><<<dim3((QKVO_N / 128) * 32), blk, 0, stream>>>(
      h_in, wT_qkvo, QKVO_N, 2048, nullptr, nullptr, qkvo);

  vtrans_kernel<<<dim3(32, 4, 16), blk, 0, stream>>>(qkvo, vtbuf);
  attn_kernel<<<dim3(32, 16), blk, 0, stream>>>(qkvo, vtbuf, ftb, Gbuf, mbuf, mh_w, h_out);

  gemm_kernel<1><<<dim3(16 * 32), blk, 0, stream>>>(
      h_out, wT_out, 2048, 2048, out, x, nullptr);

  rmsnorm_kernel<false><<<MROWS, blk, 0, stream>>>(out, n2w, h_in,
      nullptr, nullptr, nullptr, nullptr, nullptr);

  // fused gate+up: N=16384 interleaved, epilogue silu(g)*u -> tbuf [4096][8192]
  gemm_kernel<5><<<dim3((2 * FF / 128) * 32), blk, 0, stream>>>(
      h_in, wT_gu, 2 * FF, 2048, nullptr, nullptr, tbuf);
  gemm_kernel<3><<<dim3(16 * 32), blk, 0, stream>>>(
      tbuf, wT_down, 2048, FF, out, nullptr, nullptr);
}